// Round 1
// baseline (805.422 us; speedup 1.0000x reference)
//
#include <hip/hip_runtime.h>
#include <math.h>

#define B_ 32
#define T_ 2048
#define H_ 1024

typedef __bf16 bf16x8 __attribute__((ext_vector_type(8)));
typedef float f32x4 __attribute__((ext_vector_type(4)));

__device__ __forceinline__ unsigned short f2bf(float f) {
  unsigned int u = __float_as_uint(f);
  u += 0x7fffu + ((u >> 16) & 1u);   // round-to-nearest-even (finite inputs)
  return (unsigned short)(u >> 16);
}

__device__ __forceinline__ float fast_tanh(float x) {
  float e = __expf(2.0f * x);
  return 1.0f - __fdividef(2.0f, e + 1.0f);  // saturates correctly at +-1
}

// blk < 128: hxb[b,o] = x[b,:].Wq[o,:] + bq[o] + bm[o]   (32768 threads)
// blk >= 128: Wm fp32 -> bf16                             (1024 blocks)
__global__ void prep_kernel(const float* __restrict__ x, const float* __restrict__ Wq,
                            const float* __restrict__ bq, const float* __restrict__ bm,
                            const float* __restrict__ Wm,
                            float* __restrict__ hxb, unsigned short* __restrict__ wmb) {
  int blk = blockIdx.x, tid = threadIdx.x;
  if (blk < 128) {
    int idx = (blk << 8) + tid;
    int b = idx >> 10, o = idx & (H_ - 1);
    const float4* xr = (const float4*)(x + b * H_);
    const float4* wr = (const float4*)(Wq + o * H_);
    float s = 0.f;
#pragma unroll 8
    for (int h = 0; h < H_ / 4; ++h) {
      float4 xv = xr[h], wv = wr[h];
      s += xv.x * wv.x + xv.y * wv.y + xv.z * wv.z + xv.w * wv.w;
    }
    hxb[idx] = s + bq[o] + bm[o];
  } else {
    int i = ((blk - 128) << 10) + (tid << 2);
    float4 wv = *(const float4*)(Wm + i);
    *(ushort4*)(wmb + i) = make_ushort4(f2bf(wv.x), f2bf(wv.y), f2bf(wv.z), f2bf(wv.w));
  }
}

// One block per 128-row t-tile (512 blocks). Loops all 8 o-tiles internally:
// MFMA 128x128 accumulate -> epilogue tanh(acc + hxb) * v -> reduce over o -> logits.
__global__ __launch_bounds__(256) void score_kernel(
    const float* __restrict__ ctx, const unsigned short* __restrict__ wmb,
    const float* __restrict__ hxb, const float* __restrict__ v,
    float* __restrict__ logits) {
  __shared__ __align__(16) unsigned short As[128][32];  // t x k, bf16 bits
  __shared__ __align__(16) unsigned short Bs[128][32];  // o x k, bf16 bits
  __shared__ float part[128];                           // per-t logit accumulator

  int tid = threadIdx.x;
  int blk = blockIdx.x;
  int b = blk >> 4;
  int t0 = (blk & 15) << 7;
  if (tid < 128) part[tid] = 0.f;

  int lane = tid & 63;
  int wave = tid >> 6;
  int wm = (wave >> 1) << 6;  // wave's t-offset in tile (0/64)
  int wn = (wave & 1) << 6;   // wave's o-offset in tile (0/64)
  int q = lane >> 4;
  int m = lane & 15;
  const float* ctx_b = ctx + ((size_t)b * T_ + t0) * H_;

  int a_row = tid >> 3;       // A staging: 4 reps of 32 rows, 8 float4/row
  int a_c = (tid & 7) << 2;
  int b_row = tid >> 2;       // B staging: 2 reps of 64 rows, 4 uint4/row
  int b_c = (tid & 3) << 3;

  for (int ot = 0; ot < 8; ++ot) {
    int o0 = ot << 7;
    f32x4 acc[4][4];
#pragma unroll
    for (int i = 0; i < 4; ++i)
#pragma unroll
      for (int j = 0; j < 4; ++j) acc[i][j] = (f32x4){0.f, 0.f, 0.f, 0.f};
    const unsigned short* wrow = wmb + (size_t)o0 * H_;

    for (int k0 = 0; k0 < H_; k0 += 32) {
      __syncthreads();  // previous reads done before restaging
#pragma unroll
      for (int rep = 0; rep < 4; ++rep) {
        int row = a_row + (rep << 5);
        float4 fv = *(const float4*)(ctx_b + row * H_ + k0 + a_c);
        *(ushort4*)(&As[row][a_c]) =
            make_ushort4(f2bf(fv.x), f2bf(fv.y), f2bf(fv.z), f2bf(fv.w));
      }
#pragma unroll
      for (int rep = 0; rep < 2; ++rep) {
        int row = b_row + (rep << 6);
        *(uint4*)(&Bs[row][b_c]) = *(const uint4*)(wrow + row * H_ + k0 + b_c);
      }
      __syncthreads();

      bf16x8 af[4], bfr[4];
#pragma unroll
      for (int i = 0; i < 4; ++i)
        af[i] = *(const bf16x8*)(&As[wm + (i << 4) + m][q << 3]);
#pragma unroll
      for (int j = 0; j < 4; ++j)
        bfr[j] = *(const bf16x8*)(&Bs[wn + (j << 4) + m][q << 3]);
#pragma unroll
      for (int i = 0; i < 4; ++i)
#pragma unroll
        for (int j = 0; j < 4; ++j)
          acc[i][j] = __builtin_amdgcn_mfma_f32_16x16x32_bf16(af[i], bfr[j], acc[i][j], 0, 0, 0);
    }

    // epilogue: lane holds D[t = wm + i*16 + q*4 + r][o = o0 + wn + j*16 + m]
    float hb[4], vv[4];
#pragma unroll
    for (int j = 0; j < 4; ++j) {
      int o = o0 + wn + (j << 4) + m;
      hb[j] = hxb[(b << 10) + o];
      vv[j] = v[o];
    }
#pragma unroll
    for (int i = 0; i < 4; ++i) {
#pragma unroll
      for (int r = 0; r < 4; ++r) {
        float s = 0.f;
#pragma unroll
        for (int j = 0; j < 4; ++j) s += fast_tanh(acc[i][j][r] + hb[j]) * vv[j];
        s += __shfl_xor(s, 1);
        s += __shfl_xor(s, 2);
        s += __shfl_xor(s, 4);
        s += __shfl_xor(s, 8);
        if (m == 0) atomicAdd(&part[wm + (i << 4) + (q << 2) + r], s);
      }
    }
  }
  __syncthreads();
  if (tid < 128) logits[b * T_ + t0 + tid] = part[tid];
}

__global__ void softmax_kernel(const float* __restrict__ logits, float* __restrict__ score) {
  int b = blockIdx.x, tid = threadIdx.x;
  __shared__ float wmax[4], wsum[4];
  const float* lb = logits + b * T_;
  float l[8];
  float mx = -3.4e38f;
#pragma unroll
  for (int i = 0; i < 8; ++i) { l[i] = lb[tid + (i << 8)]; mx = fmaxf(mx, l[i]); }
#pragma unroll
  for (int d = 1; d < 64; d <<= 1) mx = fmaxf(mx, __shfl_xor(mx, d));
  if ((tid & 63) == 0) wmax[tid >> 6] = mx;
  __syncthreads();
  mx = fmaxf(fmaxf(wmax[0], wmax[1]), fmaxf(wmax[2], wmax[3]));
  float e[8];
  float se = 0.f;
#pragma unroll
  for (int i = 0; i < 8; ++i) { e[i] = __expf(l[i] - mx); se += e[i]; }
#pragma unroll
  for (int d = 1; d < 64; d <<= 1) se += __shfl_xor(se, d);
  if ((tid & 63) == 0) wsum[tid >> 6] = se;
  __syncthreads();
  se = wsum[0] + wsum[1] + wsum[2] + wsum[3];
  float inv = 1.0f / se;
#pragma unroll
  for (int i = 0; i < 8; ++i) score[b * T_ + tid + (i << 8)] = e[i] * inv;
}

// c[b,h] = sum_t ctx[b,t,h] * score[b,t]; grid (H/256, T/256, B), atomicAdd into zeroed c.
__global__ void wsum_kernel(const float* __restrict__ ctx, const float* __restrict__ score,
                            float* __restrict__ outc) {
  int tid = threadIdx.x;
  int h = (blockIdx.x << 8) + tid;
  int tch = blockIdx.y << 8;
  int b = blockIdx.z;
  __shared__ float sc[256];
  sc[tid] = score[b * T_ + tch + tid];
  __syncthreads();
  const float* cb = ctx + ((size_t)b * T_ + tch) * H_ + h;
  float s = 0.f;
#pragma unroll 4
  for (int t = 0; t < 256; ++t) s += cb[(size_t)t * H_] * sc[t];
  atomicAdd(&outc[(b << 10) + h], s);
}

extern "C" void kernel_launch(void* const* d_in, const int* in_sizes, int n_in,
                              void* d_out, int out_size, void* d_ws, size_t ws_size,
                              hipStream_t stream) {
  const float* x   = (const float*)d_in[0];
  const float* ctx = (const float*)d_in[1];
  // d_in[2] = mask, unused by the reference
  const float* Wq  = (const float*)d_in[3];
  const float* bq  = (const float*)d_in[4];
  const float* Wm  = (const float*)d_in[5];
  const float* bm  = (const float*)d_in[6];
  const float* v   = (const float*)d_in[7];

  float* out_c = (float*)d_out;            // [B,H]
  float* out_s = out_c + B_ * H_;          // [B,T]

  char* ws = (char*)d_ws;
  float* hxb = (float*)ws;                                            // 128 KiB
  unsigned short* wmb = (unsigned short*)(ws + (size_t)B_ * H_ * 4);  // 2 MiB
  float* logits = (float*)(ws + (size_t)B_ * H_ * 4 + (size_t)H_ * H_ * 2);  // 256 KiB

  hipMemsetAsync(out_c, 0, B_ * H_ * sizeof(float), stream);
  prep_kernel<<<dim3(128 + 1024), 256, 0, stream>>>(x, Wq, bq, bm, Wm, hxb, wmb);
  score_kernel<<<dim3(512), 256, 0, stream>>>(ctx, wmb, hxb, v, logits);
  softmax_kernel<<<dim3(B_), 256, 0, stream>>>(logits, out_s);
  wsum_kernel<<<dim3(H_ / 256, T_ / 256, B_), 256, 0, stream>>>(ctx, out_s, out_c);
}

// Round 2
// 753.041 us; speedup vs baseline: 1.0696x; 1.0696x over previous
//
#include <hip/hip_runtime.h>
#include <math.h>

#define B_ 32
#define T_ 2048
#define H_ 1024

typedef __bf16 bf16x8 __attribute__((ext_vector_type(8)));
typedef float f32x4 __attribute__((ext_vector_type(4)));

__device__ __forceinline__ unsigned short f2bf(float f) {
  unsigned int u = __float_as_uint(f);
  u += 0x7fffu + ((u >> 16) & 1u);   // round-to-nearest-even (finite inputs)
  return (unsigned short)(u >> 16);
}

__device__ __forceinline__ float bf2f(unsigned short s) {
  return __uint_as_float(((unsigned int)s) << 16);
}

__device__ __forceinline__ float fast_tanh(float x) {
  float e = __expf(2.0f * x);
  return 1.0f - __fdividef(2.0f, e + 1.0f);  // saturates correctly at +-1
}

// blk < 128:   hxb[b,o] = x[b,:].Wq[o,:] + bq[o] + bm[o]
// blk < 1152:  Wm fp32 -> bf16
// blk >= 1152: ctx fp32 -> bf16 (only launched when ws has room)
__global__ void prep_kernel(const float* __restrict__ x, const float* __restrict__ Wq,
                            const float* __restrict__ bq, const float* __restrict__ bm,
                            const float* __restrict__ Wm, const float* __restrict__ ctx,
                            float* __restrict__ hxb, unsigned short* __restrict__ wmb,
                            unsigned short* __restrict__ ctxb) {
  int blk = blockIdx.x, tid = threadIdx.x;
  if (blk < 128) {
    int idx = (blk << 8) + tid;
    int b = idx >> 10, o = idx & (H_ - 1);
    const float4* xr = (const float4*)(x + b * H_);
    const float4* wr = (const float4*)(Wq + o * H_);
    float s = 0.f;
#pragma unroll 8
    for (int h = 0; h < H_ / 4; ++h) {
      float4 xv = xr[h], wv = wr[h];
      s += xv.x * wv.x + xv.y * wv.y + xv.z * wv.z + xv.w * wv.w;
    }
    hxb[idx] = s + bq[o] + bm[o];
  } else if (blk < 1152) {
    int i = ((blk - 128) << 10) + (tid << 2);
    float4 wv = *(const float4*)(Wm + i);
    *(ushort4*)(wmb + i) = make_ushort4(f2bf(wv.x), f2bf(wv.y), f2bf(wv.z), f2bf(wv.w));
  } else {
    size_t i = ((size_t)(blk - 1152) << 11) + ((size_t)tid << 3);
    float4 a = *(const float4*)(ctx + i);
    float4 c = *(const float4*)(ctx + i + 4);
    *(ushort4*)(ctxb + i) = make_ushort4(f2bf(a.x), f2bf(a.y), f2bf(a.z), f2bf(a.w));
    *(ushort4*)(ctxb + i + 4) = make_ushort4(f2bf(c.x), f2bf(c.y), f2bf(c.z), f2bf(c.w));
  }
}

// One block per 128-row t-tile (512 blocks), o-tiles looped inside.
// A (ctx) staged in padded LDS (stride 72 ushorts -> conflict-free b128 r/w);
// B (Wm bf16, 2 MiB, L2-resident) loaded directly into fragments from global.
template <bool PRECONV>
__global__ __launch_bounds__(256) void score_kernel(
    const float* __restrict__ ctxf, const unsigned short* __restrict__ ctxb,
    const unsigned short* __restrict__ wmb,
    const float* __restrict__ hxb, const float* __restrict__ v,
    float* __restrict__ logits) {
  __shared__ __align__(16) unsigned short As[128][72];
  __shared__ float part[128];

  int tid = threadIdx.x;
  int blk = blockIdx.x;
  int b = blk >> 4;
  int t0 = (blk & 15) << 7;
  if (tid < 128) part[tid] = 0.f;

  int lane = tid & 63;
  int wave = tid >> 6;
  int wm = (wave >> 1) << 6;  // wave t-offset (0/64)
  int wn = (wave & 1) << 6;   // wave o-offset (0/64)
  int q = lane >> 4;
  int m = lane & 15;
  const unsigned short* cb = PRECONV ? (ctxb + ((size_t)b * T_ + t0) * H_) : nullptr;
  const float* cf = PRECONV ? nullptr : (ctxf + ((size_t)b * T_ + t0) * H_);

  int ar = tid >> 3;        // staging row 0..31 (+32 per rep)
  int ac = (tid & 7) << 3;  // staging col granule (ushort units)

  for (int ot = 0; ot < 8; ++ot) {
    int o0 = ot << 7;
    f32x4 acc[4][4];
#pragma unroll
    for (int i = 0; i < 4; ++i)
#pragma unroll
      for (int j = 0; j < 4; ++j) acc[i][j] = (f32x4){0.f, 0.f, 0.f, 0.f};

    for (int k0 = 0; k0 < H_; k0 += 64) {
      __syncthreads();
#pragma unroll
      for (int rep = 0; rep < 4; ++rep) {
        int row = ar + (rep << 5);
        if (PRECONV) {
          *(uint4*)(&As[row][ac]) = *(const uint4*)(cb + (size_t)row * H_ + k0 + ac);
        } else {
          const float* src = cf + (size_t)row * H_ + k0 + ac;
          float4 f0 = *(const float4*)(src);
          float4 f1 = *(const float4*)(src + 4);
          *(ushort4*)(&As[row][ac]) =
              make_ushort4(f2bf(f0.x), f2bf(f0.y), f2bf(f0.z), f2bf(f0.w));
          *(ushort4*)(&As[row][ac + 4]) =
              make_ushort4(f2bf(f1.x), f2bf(f1.y), f2bf(f1.z), f2bf(f1.w));
        }
      }
      __syncthreads();
#pragma unroll
      for (int kk = 0; kk < 2; ++kk) {
        bf16x8 af[4], bfr[4];
        const unsigned short* wp =
            wmb + (size_t)(o0 + wn + m) * H_ + k0 + (kk << 5) + (q << 3);
#pragma unroll
        for (int j = 0; j < 4; ++j)
          bfr[j] = *(const bf16x8*)(wp + ((size_t)(j << 4) * H_));
#pragma unroll
        for (int i = 0; i < 4; ++i)
          af[i] = *(const bf16x8*)(&As[wm + (i << 4) + m][(kk << 5) + (q << 3)]);
#pragma unroll
        for (int i = 0; i < 4; ++i)
#pragma unroll
          for (int j = 0; j < 4; ++j)
            acc[i][j] = __builtin_amdgcn_mfma_f32_16x16x32_bf16(af[i], bfr[j], acc[i][j], 0, 0, 0);
      }
    }

    // epilogue: lane holds D[t = wm + i*16 + q*4 + r][o = o0 + wn + j*16 + m]
    float hb[4], vv[4];
#pragma unroll
    for (int j = 0; j < 4; ++j) {
      int o = o0 + wn + (j << 4) + m;
      hb[j] = hxb[(b << 10) + o];
      vv[j] = v[o];
    }
#pragma unroll
    for (int i = 0; i < 4; ++i) {
#pragma unroll
      for (int r = 0; r < 4; ++r) {
        float s = 0.f;
#pragma unroll
        for (int j = 0; j < 4; ++j) s += fast_tanh(acc[i][j][r] + hb[j]) * vv[j];
        s += __shfl_xor(s, 1);
        s += __shfl_xor(s, 2);
        s += __shfl_xor(s, 4);
        s += __shfl_xor(s, 8);
        if (m == 0) atomicAdd(&part[wm + (i << 4) + (q << 2) + r], s);
      }
    }
  }
  __syncthreads();
  if (tid < 128) logits[b * T_ + t0 + tid] = part[tid];
}

__global__ void softmax_kernel(const float* __restrict__ logits, float* __restrict__ score) {
  int b = blockIdx.x, tid = threadIdx.x;
  __shared__ float wmax[4], wsum[4];
  const float* lb = logits + b * T_;
  float l[8];
  float mx = -3.4e38f;
#pragma unroll
  for (int i = 0; i < 8; ++i) { l[i] = lb[tid + (i << 8)]; mx = fmaxf(mx, l[i]); }
#pragma unroll
  for (int d = 1; d < 64; d <<= 1) mx = fmaxf(mx, __shfl_xor(mx, d));
  if ((tid & 63) == 0) wmax[tid >> 6] = mx;
  __syncthreads();
  mx = fmaxf(fmaxf(wmax[0], wmax[1]), fmaxf(wmax[2], wmax[3]));
  float e[8];
  float se = 0.f;
#pragma unroll
  for (int i = 0; i < 8; ++i) { e[i] = __expf(l[i] - mx); se += e[i]; }
#pragma unroll
  for (int d = 1; d < 64; d <<= 1) se += __shfl_xor(se, d);
  if ((tid & 63) == 0) wsum[tid >> 6] = se;
  __syncthreads();
  se = wsum[0] + wsum[1] + wsum[2] + wsum[3];
  float inv = 1.0f / se;
#pragma unroll
  for (int i = 0; i < 8; ++i) score[b * T_ + tid + (i << 8)] = e[i] * inv;
}

// c[b,h] = sum_t ctx[b,t,h]*score[b,t]; grid (H/512, T/256, B); 2 h per thread.
template <bool PRECONV>
__global__ void wsum_kernel(const float* __restrict__ ctxf, const unsigned short* __restrict__ ctxb,
                            const float* __restrict__ score, float* __restrict__ outc) {
  int tid = threadIdx.x;
  int h = (blockIdx.x << 9) + (tid << 1);
  int tch = blockIdx.y << 8;
  int b = blockIdx.z;
  __shared__ float sc[256];
  sc[tid] = score[b * T_ + tch + tid];
  __syncthreads();
  float s0 = 0.f, s1 = 0.f;
  if (PRECONV) {
    const unsigned short* cp = ctxb + ((size_t)b * T_ + tch) * H_ + h;
#pragma unroll 4
    for (int t = 0; t < 256; ++t) {
      unsigned int u = *(const unsigned int*)(cp + (size_t)t * H_);
      s0 += bf2f((unsigned short)(u & 0xffffu)) * sc[t];
      s1 += bf2f((unsigned short)(u >> 16)) * sc[t];
    }
  } else {
    const float* cp = ctxf + ((size_t)b * T_ + tch) * H_ + h;
#pragma unroll 4
    for (int t = 0; t < 256; ++t) {
      float2 f = *(const float2*)(cp + (size_t)t * H_);
      s0 += f.x * sc[t];
      s1 += f.y * sc[t];
    }
  }
  atomicAdd(&outc[(b << 10) + h], s0);
  atomicAdd(&outc[(b << 10) + h + 1], s1);
}

extern "C" void kernel_launch(void* const* d_in, const int* in_sizes, int n_in,
                              void* d_out, int out_size, void* d_ws, size_t ws_size,
                              hipStream_t stream) {
  const float* x   = (const float*)d_in[0];
  const float* ctx = (const float*)d_in[1];
  // d_in[2] = mask, unused by the reference
  const float* Wq  = (const float*)d_in[3];
  const float* bq  = (const float*)d_in[4];
  const float* Wm  = (const float*)d_in[5];
  const float* bm  = (const float*)d_in[6];
  const float* v   = (const float*)d_in[7];

  float* out_c = (float*)d_out;   // [B,H]
  float* out_s = out_c + B_ * H_; // [B,T]

  char* ws = (char*)d_ws;
  float* hxb = (float*)ws;                                   // 128 KiB
  unsigned short* wmb = (unsigned short*)(ws + 131072);      // 2 MiB
  float* logits = (float*)(ws + 131072 + 2097152);           // 256 KiB
  size_t off_ctxb = 131072 + 2097152 + 262144;
  unsigned short* ctxb = (unsigned short*)(ws + off_ctxb);   // 128 MiB
  size_t need = off_ctxb + (size_t)B_ * T_ * H_ * 2;
  bool preconv = (ws_size >= need);

  hipMemsetAsync(out_c, 0, B_ * H_ * sizeof(float), stream);
  int prep_blocks = preconv ? (1152 + 32768) : 1152;
  prep_kernel<<<dim3(prep_blocks), 256, 0, stream>>>(x, Wq, bq, bm, Wm, ctx, hxb, wmb,
                                                     preconv ? ctxb : nullptr);
  if (preconv) {
    score_kernel<true><<<dim3(512), 256, 0, stream>>>(ctx, ctxb, wmb, hxb, v, logits);
  } else {
    score_kernel<false><<<dim3(512), 256, 0, stream>>>(ctx, ctxb, wmb, hxb, v, logits);
  }
  softmax_kernel<<<dim3(B_), 256, 0, stream>>>(logits, out_s);
  if (preconv) {
    wsum_kernel<true><<<dim3(H_ / 512, T_ / 256, B_), 256, 0, stream>>>(ctx, ctxb, out_s, out_c);
  } else {
    wsum_kernel<false><<<dim3(H_ / 512, T_ / 256, B_), 256, 0, stream>>>(ctx, ctxb, out_s, out_c);
  }
}